// Round 13
// baseline (595.028 us; speedup 1.0000x reference)
//
#include <hip/hip_runtime.h>

typedef unsigned short u16;
typedef unsigned int   u32;
typedef __bf16 bf16x8 __attribute__((ext_vector_type(8)));
typedef float  f32x4  __attribute__((ext_vector_type(4)));

// packed-weight regions (bf16 elements) in d_ws
#define OFF_W2  196608
#define OFF_W3  245760
#define OFF_TG  270336
#define OFF_TW1 335872
#define OFF_TW2 352256
#define OFF_FGA 360448
#define OFF_FGB 376832
#define NPACK   409600

// native f32->bf16 (RNE): v_cvt_pk_bf16_f32
__device__ __forceinline__ u16 f2bf(float f) {
  union { __bf16 b; u16 u; } cv;
  cv.b = (__bf16)f;
  return cv.u;
}
__device__ __forceinline__ u32 f2bf2(float lo, float hi) {
  return (u32)f2bf(lo) | ((u32)f2bf(hi) << 16);
}
__device__ __forceinline__ float bflo(u32 p) { return __uint_as_float(p << 16); }
__device__ __forceinline__ float bfhi(u32 p) { return __uint_as_float(p & 0xffff0000u); }

union U4 { uint4 u; bf16x8 v; };
__device__ __forceinline__ bf16x8 ld_frag(const u16* p) {
  U4 t; t.u = *(const uint4*)p; return t.v;
}
__device__ __forceinline__ f32x4 mfma16(bf16x8 a, bf16x8 b, f32x4 c) {
  return __builtin_amdgcn_mfma_f32_16x16x32_bf16(a, b, c, 0, 0, 0);
}
__device__ __forceinline__ float swishf(float x) { return x / (1.f + __expf(-x)); }
__device__ __forceinline__ float sig2(float x) { return 2.f / (1.f + __expf(-x)); }

// ---------------- weight repack: f32 row-major -> bf16 fragment order (unchanged) ----------------
__global__ __launch_bounds__(256) void prep_pack(
    const float* __restrict__ eW1, const float* __restrict__ eW2,
    const float* __restrict__ eW3, const float* __restrict__ tgW1,
    const float* __restrict__ twW1, const float* __restrict__ twW2,
    const float* __restrict__ fgA, const float* __restrict__ fgB,
    u16* __restrict__ pk)
{
  int idx = blockIdx.x * 256 + threadIdx.x;
  if (idx >= NPACK) return;
  float v;
  if (idx < OFF_W2) {                 // exp_W1: [6][nt:8][kt:8][64][8]
    int i = idx & 7, lane = (idx >> 3) & 63, kt = (idx >> 9) & 7, nt = (idx >> 12) & 7, e = idx >> 15;
    int k = kt*32 + (lane>>4)*8 + i, n = nt*16 + (lane & 15);
    v = eW1[(e*256 + k)*128 + n];
  } else if (idx < OFF_W3) {          // exp_W2: [6][nt:4][kt:4][64][8]
    int j = idx - OFF_W2;
    int i = j & 7, lane = (j >> 3) & 63, kt = (j >> 9) & 3, nt = (j >> 11) & 3, e = j >> 13;
    int k = kt*32 + (lane>>4)*8 + i, n = nt*16 + (lane & 15);
    v = eW2[(e*128 + k)*64 + n];
  } else if (idx < OFF_TG) {          // exp_W3: [6][nt:4][kt:2][64][8]
    int j = idx - OFF_W3;
    int i = j & 7, lane = (j >> 3) & 63, kt = (j >> 9) & 1, nt = (j >> 10) & 3, e = j >> 12;
    int k = kt*32 + (lane>>4)*8 + i, n = nt*16 + (lane & 15);
    v = eW3[(e*64 + k)*64 + n];
  } else if (idx < OFF_TW1) {         // tg_W1: [4][nt:4][kt:8][64][8]
    int j = idx - OFF_TG;
    int i = j & 7, lane = (j >> 3) & 63, kt = (j >> 9) & 7, nt = (j >> 12) & 3, t = j >> 14;
    int k = kt*32 + (lane>>4)*8 + i, n = nt*16 + (lane & 15);
    v = tgW1[(t*256 + k)*64 + n];
  } else if (idx < OFF_TW2) {         // tw_W1: [4][nt:4][kt:2][64][8]
    int j = idx - OFF_TW1;
    int i = j & 7, lane = (j >> 3) & 63, kt = (j >> 9) & 1, nt = (j >> 10) & 3, t = j >> 12;
    int k = kt*32 + (lane>>4)*8 + i, n = nt*16 + (lane & 15);
    v = twW1[(t*64 + k)*64 + n];
  } else if (idx < OFF_FGA) {         // tw_W2: [4][nt:2][kt:2][64][8]
    int j = idx - OFF_TW2;
    int i = j & 7, lane = (j >> 3) & 63, kt = (j >> 9) & 1, nt = (j >> 10) & 1, t = j >> 11;
    int k = kt*32 + (lane>>4)*8 + i, n = nt*16 + (lane & 15);
    v = twW2[(t*64 + k)*32 + n];
  } else if (idx < OFF_FGB) {         // fgA^T A-frags: [4][kt:8][64][8]
    int j = idx - OFF_FGA;
    int i = j & 7, lane = (j >> 3) & 63, kt = (j >> 9) & 7, t = j >> 12;
    int m = lane & 15, k = kt*32 + (lane>>4)*8 + i;
    v = (m < 8) ? fgA[(t*256 + k)*8 + m] : 0.f;
  } else {                            // fgB^T A-frags: [4][mtile:16][64][8]
    int j = idx - OFF_FGB;
    int i = j & 7, lane = (j >> 3) & 63, mtl = (j >> 9) & 15, t = j >> 13;
    int m = mtl*16 + (lane & 15), kr = (lane>>4)*8 + i;
    v = (kr < 8) ? fgB[t*2048 + kr*256 + m] : 0.f;
  }
  pk[idx] = f2bf(v);
}

// ---------------- fused main kernel: 32 batch rows/block, M=64 task-pair-batched expert chain ----------------
// r13 = r11 (proven 346 us, VGPR 120, 2 blocks/CU) + exactly ONE register-neutral change:
// GEMM1 nn-split: outer nn, inner kt -> each W1 B-frag loaded ONCE (16 vs 32 global b128/el/wave).
// acc1[4] per nn = 16 VGPRs (same as r11's per-pass acc1[2][2]). A-frag LDS reads double (cheap).
// r12 LESSON (ledger): VGPR 148 -> occupancy 11.6% -> +70% dur. Keep VGPR <= ~128; one change/round.
__global__ __launch_bounds__(256, 3) void home_main(
    const float* __restrict__ zs, const float* __restrict__ zg0, const float* __restrict__ zg1,
    const float* __restrict__ tgW2, const float* __restrict__ tgb1, const float* __restrict__ tgb2,
    const float* __restrict__ eb1, const float* __restrict__ eb2, const float* __restrict__ eb3,
    const float* __restrict__ lns, const float* __restrict__ lnb,
    const float* __restrict__ sgW, const float* __restrict__ sgb,
    const float* __restrict__ twb1, const float* __restrict__ twb2,
    const float* __restrict__ twW3, const float* __restrict__ twb3,
    const u16* __restrict__ pk, float* __restrict__ out)
{
  __shared__ __align__(16) u16   cmfrag[4*8*64*8];   // 32768 B  [mt4][kt8][64][8]: mt0,1=t0 copy; mt2,3=t1 copy
  __shared__ __align__(16) u16   h1frag[4*4*64*8];   // 16384 B  [mt4][kt4][64][8]; alias accT f32[2][8][34]
  __shared__ __align__(16) u16   h2frag[4*2*64*8];   //  8192 B  [mt4][kt2][64][8]; alias aggfrag [8][64][8]
  __shared__ __align__(16) float fbuf[2*32*68];      // 17408 B  gh / e_pre per task; alias th1frag u16[2][2048]
  __shared__ __align__(16) float gwbuf[256];         //  1024 B  [2][32][4] softmax gate weights
  __shared__ __align__(16) float smallw[640];        //  2560 B  [2][320] tg_W2^T swizzled

  float* accT    = (float*)h1frag;   // [2][8][34] (gate phase only; dead before h1frag written)
  u16*   aggfrag = h2frag;           // [8 tiles][64][8]
  u16*   th1frag = (u16*)fbuf;       // [2][2048]

  const int tid  = threadIdx.x;
  const int lane = tid & 63;
  const int wid  = tid >> 6;       // wave 0..3
  const int r    = tid >> 3;       // row 0..31 (staging / softmax)
  const int q    = tid & 7;        // eighth of the 256-d feature
  const int rowBase = blockIdx.x * 32;
  const int mt_r = r >> 4, r15 = r & 15;
  const int rl   = (lane >> 4) * 4;   // C-layout row offset
  const int l15  = lane & 15;
  const int tkw  = wid >> 1;          // wave's task (0/1 within pair)
  const int chw  = wid & 1;           // wave's half-role
  const f32x4 fz = {0.f, 0.f, 0.f, 0.f};

  #pragma unroll 1
  for (int pair = 0; pair < 2; ++pair) {
    const int g = pair;
    const int tg0 = g*2 + tkw;       // wave's global task id

    // ---------- stage cm_pre (bf16) into BOTH task copies + tg_W2 for both tasks ----------
    {
      const float* zsrc = (q < 4)
        ? (zs + (size_t)(rowBase + r) * 128 + q * 32)
        : ((pair ? zg1 : zg0) + (size_t)(rowBase + r) * 128 + (q - 4) * 32);
      #pragma unroll
      for (int h = 0; h < 4; ++h) {
        float4 a = ((const float4*)zsrc)[2*h], b4 = ((const float4*)zsrc)[2*h+1];
        uint4 wv;
        wv.x = f2bf2(a.x, a.y);
        wv.y = f2bf2(a.z, a.w);
        wv.z = f2bf2(b4.x, b4.y);
        wv.w = f2bf2(b4.z, b4.w);
        *(uint4*)&cmfrag[((mt_r*8 + q)*64 + r15 + 16*h)*8] = wv;
        *(uint4*)&cmfrag[(((mt_r+2)*8 + q)*64 + r15 + 16*h)*8] = wv;
      }
    }
    #pragma unroll
    for (int tk = 0; tk < 2; ++tk) {
      int e = tid >> 6, c = tid & 63, half = c >> 5, cl = c & 31;
      smallw[tk*320 + (e*2 + half)*36 + cl] = tgW2[(g*2+tk)*256 + c*4 + e];
    }
    __syncthreads();   // A

    // prefetch fgB^T A-frags (first 4 of this wave's 8 mtiles)
    const u16* fgbp = pk + OFF_FGB + (tg0*16 + chw*8)*512 + lane*8;
    U4 afg[4];
    #pragma unroll
    for (int m4 = 0; m4 < 4; ++m4) afg[m4].u = *(const uint4*)(fgbp + m4*512);

    // ---------- gate step 1 (all 4 waves): accT[tk](8x32) = fgA^T @ cm_pre^T ----------
    {
      f32x4 d1 = fz;
      const u16* ap = pk + OFF_FGA + (tg0*8)*512 + lane*8;
      #pragma unroll
      for (int kt = 0; kt < 8; ++kt) {
        bf16x8 af = ld_frag(ap + kt*512);
        bf16x8 bf = ld_frag(&cmfrag[(((2*tkw + chw)*8 + kt)*64 + lane)*8]);
        d1 = mfma16(af, bf, d1);
      }
      if (rl < 8) {
        #pragma unroll
        for (int rr = 0; rr < 4; ++rr)
          accT[tkw*272 + (rl + rr)*34 + chw*16 + l15] = d1[rr];
      }
    }
    __syncthreads();   // A2

    // ---------- gate step 2 + in-place apply: logits = fgB^T @ accT; cm *= 2*sigmoid ----------
    {
      U4 b0u, b1u;
      if (lane < 16) {
        float v0[8], v1[8];
        #pragma unroll
        for (int i = 0; i < 8; ++i) {
          v0[i] = accT[tkw*272 + i*34 + l15];
          v1[i] = accT[tkw*272 + i*34 + 16 + l15];
        }
        b0u.u.x = f2bf2(v0[0], v0[1]); b0u.u.y = f2bf2(v0[2], v0[3]);
        b0u.u.z = f2bf2(v0[4], v0[5]); b0u.u.w = f2bf2(v0[6], v0[7]);
        b1u.u.x = f2bf2(v1[0], v1[1]); b1u.u.y = f2bf2(v1[2], v1[3]);
        b1u.u.z = f2bf2(v1[4], v1[5]); b1u.u.w = f2bf2(v1[6], v1[7]);
      } else {
        b0u.u = make_uint4(0, 0, 0, 0);
        b1u.u = make_uint4(0, 0, 0, 0);
      }
      const int i0 = rl & 7;              // 0 or 4
      const int hlo = rl >> 3;            // 0 or 1
      #pragma unroll
      for (int m8 = 0; m8 < 8; ++m8) {
        int mtile = chw*8 + m8;
        bf16x8 af = (m8 < 4) ? afg[m8].v : ld_frag(fgbp + m8*512);
        f32x4 d0 = mfma16(af, b0u.v, fz);
        f32x4 d1 = mfma16(af, b1u.v, fz);
        int ktc = mtile >> 1;
        int hh  = (mtile & 1)*2 + hlo;
        // rows 0-15 of this task -> mt = 2*tkw
        {
          u16* cp = &cmfrag[(((2*tkw)*8 + ktc)*64 + l15 + 16*hh)*8 + i0];
          u32 za = ((u32*)cp)[0], zb = ((u32*)cp)[1];
          float g0 = sig2(d0[0]), g1 = sig2(d0[1]), g2 = sig2(d0[2]), g3 = sig2(d0[3]);
          ((u32*)cp)[0] = f2bf2(bflo(za)*g0, bfhi(za)*g1);
          ((u32*)cp)[1] = f2bf2(bflo(zb)*g2, bfhi(zb)*g3);
        }
        // rows 16-31 -> mt = 2*tkw+1
        {
          u16* cp = &cmfrag[(((2*tkw + 1)*8 + ktc)*64 + l15 + 16*hh)*8 + i0];
          u32 za = ((u32*)cp)[0], zb = ((u32*)cp)[1];
          float g0 = sig2(d1[0]), g1 = sig2(d1[1]), g2 = sig2(d1[2]), g3 = sig2(d1[3]);
          ((u32*)cp)[0] = f2bf2(bflo(za)*g0, bfhi(za)*g1);
          ((u32*)cp)[1] = f2bf2(bflo(zb)*g2, bfhi(zb)*g3);
        }
      }
    }
    // prefetch tg_W1 kt0 for both of this wave's n-tiles (consumed right after A3)
    const u16* wp_tg = pk + OFF_TG + ((tg0*4 + chw*2)*8)*512 + lane*8;
    U4 tgp0, tgp1;
    tgp0.u = *(const uint4*)wp_tg;
    tgp1.u = *(const uint4*)(wp_tg + 4096);
    __syncthreads();   // A3

    // ---------- task gate layer1: wave (tk=wid>>1) computes n-tiles chw*2, chw*2+1 ----------
    {
      f32x4 accg[2][2] = { { fz, fz }, { fz, fz } };   // [mtl][nt2]
      #pragma unroll
      for (int kt = 0; kt < 8; ++kt) {
        bf16x8 b0 = (kt == 0) ? tgp0.v : ld_frag(wp_tg + kt*512);
        bf16x8 b1 = (kt == 0) ? tgp1.v : ld_frag(wp_tg + 4096 + kt*512);
        #pragma unroll
        for (int mtl = 0; mtl < 2; ++mtl) {
          bf16x8 a = ld_frag(&cmfrag[(((2*tkw + mtl)*8 + kt)*64 + lane)*8]);
          accg[mtl][0] = mfma16(a, b0, accg[mtl][0]);
          accg[mtl][1] = mfma16(a, b1, accg[mtl][1]);
        }
      }
      #pragma unroll
      for (int nt2 = 0; nt2 < 2; ++nt2) {
        int colg = (chw*2 + nt2)*16 + l15;
        float bias = tgb1[tg0*64 + colg];
        #pragma unroll
        for (int mtl = 0; mtl < 2; ++mtl)
          #pragma unroll
          for (int rr = 0; rr < 4; ++rr)
            fbuf[(tkw*32 + mtl*16 + rl + rr)*68 + colg] = swishf(accg[mtl][nt2][rr] + bias);
      }
    }
    __syncthreads();   // C

    // ---------- task gate layer2 + softmax, both tasks ----------
    #pragma unroll
    for (int tk = 0; tk < 2; ++tk) {
      int e = q & 3, half = q >> 2;
      float part = 0.f;
      #pragma unroll
      for (int cj = 0; cj < 8; ++cj) {
        float4 g4 = *(const float4*)&fbuf[(tk*32 + r)*68 + half*32 + cj*4];
        float4 w4 = *(const float4*)&smallw[tk*320 + (e*2 + half)*36 + cj*4];
        part += g4.x*w4.x + g4.y*w4.y + g4.z*w4.z + g4.w*w4.w;
      }
      part += __shfl_xor(part, 4);
      float logit = part + tgb2[(g*2+tk)*4 + e];
      float mx = fmaxf(logit, __shfl_xor(logit, 1));
      mx = fmaxf(mx, __shfl_xor(mx, 2));
      float ex = __expf(logit - mx);
      float sm = ex + __shfl_xor(ex, 1);
      sm += __shfl_xor(sm, 2);
      if (q < 4) gwbuf[tk*128 + r*4 + q] = ex / sm;
    }
    // NO barrier: gwbuf first read (LN el0) is >=3 barriers downstream; GEMM1 writes h1frag
    // (accT alias dead since A3).

    // ---------- expert loop: M=64 (both tasks) ----------
    float agg[16];
    #pragma unroll
    for (int c = 0; c < 16; ++c) agg[c] = 0.f;

    const int mL  = tid >> 2;        // LN row 0..63
    const int qc  = tid & 3;         // LN col quarter (16 cols)
    const int tkL = mL >> 5, mrL = mL & 31;

    #pragma unroll 1
    for (int el = 0; el < 4; ++el) {
      const int ei = (el < 2) ? el : (el + 2*g);

      // GEMM1: cm(64x256) @ W1(256x128); wave owns n-tiles 2w,2w+1.
      // nn-split: outer nn, inner kt -> each W1 B-frag loaded ONCE (r11's 2-pass loaded all twice).
      // acc1[4] = 16 VGPRs per nn, identical register profile to r11.
      const u16* w1p = pk + ((ei*8 + 2*wid)*8)*512 + lane*8;
      #pragma unroll 1
      for (int nn = 0; nn < 2; ++nn) {
        f32x4 acc1[4] = { fz, fz, fz, fz };
        #pragma unroll
        for (int kt = 0; kt < 8; ++kt) {
          bf16x8 b0 = ld_frag(w1p + nn*4096 + kt*512);
          #pragma unroll
          for (int mt = 0; mt < 4; ++mt) {
            bf16x8 a = ld_frag(&cmfrag[((mt*8 + kt)*64 + lane)*8]);
            acc1[mt] = mfma16(a, b0, acc1[mt]);
          }
        }
        int col = (2*wid + nn)*16 + l15;
        float bias = eb1[ei*128 + col];
        int kt2 = col >> 5, h2 = (col >> 3) & 3, i2 = col & 7;
        #pragma unroll
        for (int mt = 0; mt < 4; ++mt)
          #pragma unroll
          for (int rr = 0; rr < 4; ++rr)
            h1frag[((mt*4 + kt2)*64 + rl + rr + 16*h2)*8 + i2] = f2bf(swishf(acc1[mt][rr] + bias));
      }
      // prefetch W2 kt0,1 (consumed right after E1)
      const u16* w2p = pk + OFF_W2 + ((ei*4 + wid)*4)*512 + lane*8;
      U4 w2f0, w2f1;
      w2f0.u = *(const uint4*)w2p;
      w2f1.u = *(const uint4*)(w2p + 512);
      __syncthreads();  // E1

      // GEMM2: h1(64x128) @ W2(128x64); wave owns n-tile w
      f32x4 acc2[4] = { fz, fz, fz, fz };
      #pragma unroll
      for (int kt = 0; kt < 4; ++kt) {
        bf16x8 b0 = (kt == 0) ? w2f0.v : (kt == 1) ? w2f1.v : ld_frag(w2p + kt*512);
        #pragma unroll
        for (int mt = 0; mt < 4; ++mt) {
          bf16x8 a = ld_frag(&h1frag[((mt*4 + kt)*64 + lane)*8]);
          acc2[mt] = mfma16(a, b0, acc2[mt]);
        }
      }
      // prefetch W3 both frags (consumed right after E2)
      const u16* w3p = pk + OFF_W3 + ((ei*4 + wid)*2)*512 + lane*8;
      U4 w3f0, w3f1;
      w3f0.u = *(const uint4*)w3p;
      w3f1.u = *(const uint4*)(w3p + 512);
      {
        int col = wid*16 + l15;
        float bias = eb2[ei*64 + col];
        int kt2 = col >> 5, h2 = (col >> 3) & 3, i2 = col & 7;
        #pragma unroll
        for (int mt = 0; mt < 4; ++mt)
          #pragma unroll
          for (int rr = 0; rr < 4; ++rr)
            h2frag[((mt*2 + kt2)*64 + rl + rr + 16*h2)*8 + i2] = f2bf(swishf(acc2[mt][rr] + bias));
      }
      __syncthreads();  // E2

      // GEMM3: h2(64x64) @ W3(64x64) -> e_pre into fbuf (per-task halves)
      f32x4 acc3[4] = { fz, fz, fz, fz };
      #pragma unroll
      for (int kt = 0; kt < 2; ++kt) {
        bf16x8 b0 = (kt == 0) ? w3f0.v : w3f1.v;
        #pragma unroll
        for (int mt = 0; mt < 4; ++mt) {
          bf16x8 a = ld_frag(&h2frag[((mt*2 + kt)*64 + lane)*8]);
          acc3[mt] = mfma16(a, b0, acc3[mt]);
        }
      }
      {
        int col = wid*16 + l15;
        float bias = eb3[ei*64 + col];
        #pragma unroll
        for (int mt = 0; mt < 4; ++mt)
          #pragma unroll
          for (int rr = 0; rr < 4; ++rr) {
            int m = mt*16 + rl + rr;
            fbuf[((m >> 5)*32 + (m & 31))*68 + col] = acc3[mt][rr] + bias;
          }
      }
      __syncthreads();  // E3

      // LayerNorm + self-gate diag + weighted aggregate (thread: row mL, 16 cols qc*16..)
      {
        float v[16];
        #pragma unroll
        for (int cc = 0; cc < 4; ++cc) {
          float4 f = *(const float4*)&fbuf[(tkL*32 + mrL)*68 + qc*16 + cc*4];
          v[cc*4+0] = f.x; v[cc*4+1] = f.y; v[cc*4+2] = f.z; v[cc*4+3] = f.w;
        }
        float s1 = 0.f;
        #pragma unroll
        for (int c = 0; c < 16; ++c) s1 += v[c];
        s1 += __shfl_xor(s1, 1); s1 += __shfl_xor(s1, 2);
        float mu = s1 * (1.f/64.f);
        float s2 = 0.f;
        #pragma unroll
        for (int c = 0; c < 16; ++c) { float d = v[c] - mu; s2 += d*d; }
        s2 += __shfl_xor(s2, 1); s2 += __shfl_xor(s2, 2);
        float rs = rsqrtf(s2 * (1.f/64.f) + 1e-5f);
        const int tgL = g*2 + tkL;
        const float* lsp = lns + ei*64 + qc*16;
        const float* lbp = lnb + ei*64 + qc*16;
        const float* sgp = sgW + (tgL*64 + qc*16)*4 + el;
        float swp = 0.f;
        #pragma unroll
        for (int c = 0; c < 16; ++c) {
          float eh = (v[c] - mu) * rs * lsp[c] + lbp[c];
          v[c] = eh;
          swp += eh * sgp[c*4];
        }
        swp += __shfl_xor(swp, 1); swp += __shfl_xor(swp, 2);
        swp += sgb[tgL*4 + el];
        float fac = swp * gwbuf[tkL*128 + mrL*4 + el];
        #pragma unroll
        for (int c = 0; c < 16; ++c) agg[c] += v[c] * fac;
      }
      // no trailing barrier: next GEMM1 writes h1frag (disjoint from fbuf/gwbuf); E1 orders.
    }  // expert loop

    // ---------- tower: agg(64x64) -> T1 (per task 32x64) -> T2 (32x32) -> out ----------
    {
      // write agg as A-frags: thread row mL, feats qc*16+0..15 (2 b128)
      #pragma unroll
      for (int jh = 0; jh < 2; ++jh) {
        uint4 wv;
        wv.x = f2bf2(agg[jh*8+0], agg[jh*8+1]);
        wv.y = f2bf2(agg[jh*8+2], agg[jh*8+3]);
        wv.z = f2bf2(agg[jh*8+4], agg[jh*8+5]);
        wv.w = f2bf2(agg[jh*8+6], agg[jh*8+7]);
        int tile = (mL >> 4)*2 + (qc >> 1);
        int slot = (mL & 15) + 16*((qc & 1)*2 + jh);
        *(uint4*)&aggfrag[(tile*64 + slot)*8] = wv;
      }
    }
    // prefetch tw_W1 kt0 for both of this wave's n-tiles
    const u16* tw1b = pk + OFF_TW1 + ((tg0*4 + chw*2)*2)*512 + lane*8;
    U4 t1f0, t1f1;
    t1f0.u = *(const uint4*)tw1b;
    t1f1.u = *(const uint4*)(tw1b + 1024);
    __syncthreads();  // F

    // T1: wave (task tkw) computes n-tiles chw*2, chw*2+1 of its task's 64 cols
    {
      f32x4 at1[2][2] = { { fz, fz }, { fz, fz } };   // [mtl][nt2]
      #pragma unroll
      for (int kt = 0; kt < 2; ++kt) {
        bf16x8 b0 = (kt == 0) ? t1f0.v : ld_frag(tw1b + kt*512);
        bf16x8 b1 = (kt == 0) ? t1f1.v : ld_frag(tw1b + 1024 + kt*512);
        #pragma unroll
        for (int mtl = 0; mtl < 2; ++mtl) {
          bf16x8 a = ld_frag(&aggfrag[(((2*tkw + mtl)*2 + kt)*64 + lane)*8]);
          at1[mtl][0] = mfma16(a, b0, at1[mtl][0]);
          at1[mtl][1] = mfma16(a, b1, at1[mtl][1]);
        }
      }
      #pragma unroll
      for (int nt2 = 0; nt2 < 2; ++nt2) {
        int colT = (chw*2 + nt2)*16 + l15;
        float bias = twb1[tg0*64 + colT];
        int ktT = colT >> 5, hT = (colT >> 3) & 3, iT = colT & 7;
        #pragma unroll
        for (int mtl = 0; mtl < 2; ++mtl)
          #pragma unroll
          for (int rr = 0; rr < 4; ++rr)
            th1frag[tkw*2048 + ((mtl*2 + ktT)*64 + rl + rr + 16*hT)*8 + iT] =
                f2bf(swishf(at1[mtl][nt2][rr] + bias));
      }
    }
    __syncthreads();  // G

    // T2 + output: wave w<2 handles task w entirely (both 16-col tiles), writes out.
    if (wid < 2) {
      const int tg = g*2 + wid;
      f32x4 at2[2][2] = { { fz, fz }, { fz, fz } };   // [nt][mtl]
      const u16* tw2p = pk + OFF_TW2 + (tg*2*2)*512 + lane*8;
      #pragma unroll
      for (int kt = 0; kt < 2; ++kt) {
        bf16x8 b0 = ld_frag(tw2p + kt*512);
        bf16x8 b1 = ld_frag(tw2p + 1024 + kt*512);
        #pragma unroll
        for (int mtl = 0; mtl < 2; ++mtl) {
          bf16x8 a = ld_frag(&th1frag[wid*2048 + ((mtl*2 + kt)*64 + lane)*8]);
          at2[0][mtl] = mfma16(a, b0, at2[0][mtl]);
          at2[1][mtl] = mfma16(a, b1, at2[1][mtl]);
        }
      }
      float pxs[8];
      #pragma unroll
      for (int nt = 0; nt < 2; ++nt) {
        int colU = nt*16 + l15;
        float b2  = twb2[tg*32 + colU];
        float w3v = twW3[tg*32 + colU];
        #pragma unroll
        for (int mtl = 0; mtl < 2; ++mtl)
          #pragma unroll
          for (int rr = 0; rr < 4; ++rr) {
            float val = swishf(at2[nt][mtl][rr] + b2) * w3v;
            if (nt == 0) pxs[mtl*4 + rr] = val;
            else         pxs[mtl*4 + rr] += val;
          }
      }
      #pragma unroll
      for (int k = 0; k < 8; ++k) {
        pxs[k] += __shfl_xor(pxs[k], 1);
        pxs[k] += __shfl_xor(pxs[k], 2);
        pxs[k] += __shfl_xor(pxs[k], 4);
        pxs[k] += __shfl_xor(pxs[k], 8);
      }
      if (l15 == 0) {
        float b3 = twb3[tg];
        #pragma unroll
        for (int mtl = 0; mtl < 2; ++mtl)
          #pragma unroll
          for (int rr = 0; rr < 4; ++rr) {
            int row = mtl*16 + rl + rr;
            float x = pxs[mtl*4 + rr] + b3;
            out[(size_t)(rowBase + row)*4 + tg] = 1.f / (1.f + __expf(-x));
          }
      }
    }
    // no trailing barrier: next pair's staging writes cmfrag/smallw whose last readers
    // (GEMM1 el3 / softmax) are many barriers back; th1frag (fbuf) readers here are
    // waves 0,1 only, and next writes to that region (tg1 epilogue) are behind A/A2/A3.
  }
}

extern "C" void kernel_launch(void* const* d_in, const int* in_sizes, int n_in,
                              void* d_out, int out_size, void* d_ws, size_t ws_size,
                              hipStream_t stream)
{
  (void)in_sizes; (void)n_in; (void)out_size; (void)ws_size;
  const float* zs   = (const float*)d_in[0];
  const float* zg0  = (const float*)d_in[1];
  const float* zg1  = (const float*)d_in[2];
  // d_in[3] = v : unused by the reference
  const float* eW1  = (const float*)d_in[4];
  const float* eb1  = (const float*)d_in[5];
  const float* eW2  = (const float*)d_in[6];
  const float* eb2  = (const float*)d_in[7];
  const float* eW3  = (const float*)d_in[8];
  const float* eb3  = (const float*)d_in[9];
  const float* lns  = (const float*)d_in[10];
  const float* lnb  = (const float*)d_in[11];
  const float* fgA  = (const float*)d_in[12];
  const float* fgB  = (const float*)d_in[13];
  const float* tgW1 = (const float*)d_in[14];
  const float* tgb1 = (const float*)d_in[15];
  const float* tgW2 = (const float*)d_in[16];
  const float* tgb2 = (const float*)d_in[17];
  const float* sgW  = (const float*)d_in[18];
  const float* sgb  = (const float*)d_in[19];
  const float* twW1 = (const float*)d_in[20];
  const float* twb1 = (const float*)d_in[21];
  const float* twW2 = (const float*)d_in[22];
  const float* twb2 = (const float*)d_in[23];
  const float* twW3 = (const float*)d_in[24];
  const float* twb3 = (const float*)d_in[25];

  u16* pkw = (u16*)d_ws;          // needs 819200 B
  float* outp = (float*)d_out;

  prep_pack<<<(NPACK + 255)/256, 256, 0, stream>>>(eW1, eW2, eW3, tgW1, twW1, twW2, fgA, fgB, pkw);
  home_main<<<65536/32, 256, 0, stream>>>(zs, zg0, zg1, tgW2, tgb1, tgb2,
      eb1, eb2, eb3, lns, lnb, sgW, sgb, twb1, twb2, twW3, twb3,
      pkw, outp);
}

// Round 14
// 345.722 us; speedup vs baseline: 1.7211x; 1.7211x over previous
//
#include <hip/hip_runtime.h>

typedef unsigned short u16;
typedef unsigned int   u32;
typedef __bf16 bf16x8 __attribute__((ext_vector_type(8)));
typedef float  f32x4  __attribute__((ext_vector_type(4)));

// packed-weight regions (bf16 elements) in d_ws
#define OFF_W2  196608
#define OFF_W3  245760
#define OFF_TG  270336
#define OFF_TW1 335872
#define OFF_TW2 352256
#define OFF_FGA 360448
#define OFF_FGB 376832
#define NPACK   409600

// native f32->bf16 (RNE): v_cvt_pk_bf16_f32
__device__ __forceinline__ u16 f2bf(float f) {
  union { __bf16 b; u16 u; } cv;
  cv.b = (__bf16)f;
  return cv.u;
}
__device__ __forceinline__ u32 f2bf2(float lo, float hi) {
  return (u32)f2bf(lo) | ((u32)f2bf(hi) << 16);
}
__device__ __forceinline__ float bflo(u32 p) { return __uint_as_float(p << 16); }
__device__ __forceinline__ float bfhi(u32 p) { return __uint_as_float(p & 0xffff0000u); }

union U4 { uint4 u; bf16x8 v; };
__device__ __forceinline__ bf16x8 ld_frag(const u16* p) {
  U4 t; t.u = *(const uint4*)p; return t.v;
}
__device__ __forceinline__ f32x4 mfma16(bf16x8 a, bf16x8 b, f32x4 c) {
  return __builtin_amdgcn_mfma_f32_16x16x32_bf16(a, b, c, 0, 0, 0);
}
__device__ __forceinline__ float swishf(float x) { return x / (1.f + __expf(-x)); }
__device__ __forceinline__ float sig2(float x) { return 2.f / (1.f + __expf(-x)); }

// ---------------- weight repack: f32 row-major -> bf16 fragment order (unchanged) ----------------
__global__ __launch_bounds__(256) void prep_pack(
    const float* __restrict__ eW1, const float* __restrict__ eW2,
    const float* __restrict__ eW3, const float* __restrict__ tgW1,
    const float* __restrict__ twW1, const float* __restrict__ twW2,
    const float* __restrict__ fgA, const float* __restrict__ fgB,
    u16* __restrict__ pk)
{
  int idx = blockIdx.x * 256 + threadIdx.x;
  if (idx >= NPACK) return;
  float v;
  if (idx < OFF_W2) {                 // exp_W1: [6][nt:8][kt:8][64][8]
    int i = idx & 7, lane = (idx >> 3) & 63, kt = (idx >> 9) & 7, nt = (idx >> 12) & 7, e = idx >> 15;
    int k = kt*32 + (lane>>4)*8 + i, n = nt*16 + (lane & 15);
    v = eW1[(e*256 + k)*128 + n];
  } else if (idx < OFF_W3) {          // exp_W2: [6][nt:4][kt:4][64][8]
    int j = idx - OFF_W2;
    int i = j & 7, lane = (j >> 3) & 63, kt = (j >> 9) & 3, nt = (j >> 11) & 3, e = j >> 13;
    int k = kt*32 + (lane>>4)*8 + i, n = nt*16 + (lane & 15);
    v = eW2[(e*128 + k)*64 + n];
  } else if (idx < OFF_TG) {          // exp_W3: [6][nt:4][kt:2][64][8]
    int j = idx - OFF_W3;
    int i = j & 7, lane = (j >> 3) & 63, kt = (j >> 9) & 1, nt = (j >> 10) & 3, e = j >> 12;
    int k = kt*32 + (lane>>4)*8 + i, n = nt*16 + (lane & 15);
    v = eW3[(e*64 + k)*64 + n];
  } else if (idx < OFF_TW1) {         // tg_W1: [4][nt:4][kt:8][64][8]
    int j = idx - OFF_TG;
    int i = j & 7, lane = (j >> 3) & 63, kt = (j >> 9) & 7, nt = (j >> 12) & 3, t = j >> 14;
    int k = kt*32 + (lane>>4)*8 + i, n = nt*16 + (lane & 15);
    v = tgW1[(t*256 + k)*64 + n];
  } else if (idx < OFF_TW2) {         // tw_W1: [4][nt:4][kt:2][64][8]
    int j = idx - OFF_TW1;
    int i = j & 7, lane = (j >> 3) & 63, kt = (j >> 9) & 1, nt = (j >> 10) & 3, t = j >> 12;
    int k = kt*32 + (lane>>4)*8 + i, n = nt*16 + (lane & 15);
    v = twW1[(t*64 + k)*64 + n];
  } else if (idx < OFF_FGA) {         // tw_W2: [4][nt:2][kt:2][64][8]
    int j = idx - OFF_TW2;
    int i = j & 7, lane = (j >> 3) & 63, kt = (j >> 9) & 1, nt = (j >> 10) & 1, t = j >> 11;
    int k = kt*32 + (lane>>4)*8 + i, n = nt*16 + (lane & 15);
    v = twW2[(t*64 + k)*32 + n];
  } else if (idx < OFF_FGB) {         // fgA^T A-frags: [4][kt:8][64][8]
    int j = idx - OFF_FGA;
    int i = j & 7, lane = (j >> 3) & 63, kt = (j >> 9) & 7, t = j >> 12;
    int m = lane & 15, k = kt*32 + (lane>>4)*8 + i;
    v = (m < 8) ? fgA[(t*256 + k)*8 + m] : 0.f;
  } else {                            // fgB^T A-frags: [4][mtile:16][64][8]
    int j = idx - OFF_FGB;
    int i = j & 7, lane = (j >> 3) & 63, mtl = (j >> 9) & 15, t = j >> 13;
    int m = mtl*16 + (lane & 15), kr = (lane>>4)*8 + i;
    v = (kr < 8) ? fgB[t*2048 + kr*256 + m] : 0.f;
  }
  pk[idx] = f2bf(v);
}

// ---------------- fused main kernel: 32 batch rows/block, M=64 task-pair-batched expert chain ----------------
// r14 = r11 VERBATIM (proven 346 us, VGPR 120, 2 blocks/CU, no spill).
// Ledger: r12 (merged GEMM1 + in-reg gate + deep prefetch) -> VGPR 148, occ 11.6%, 589 us.
//         r13 (GEMM1 nn-split)                             -> VGPR 144, occ 11.8%, 595 us.
// Any structural edit to the expert-loop body perturbs regalloc past the 128-reg/2-block
// cliff on this toolchain. r11's exact shape is the measured optimum; do not modify the
// expert loop without checking VGPR_Count <= 128 stays true.
__global__ __launch_bounds__(256, 3) void home_main(
    const float* __restrict__ zs, const float* __restrict__ zg0, const float* __restrict__ zg1,
    const float* __restrict__ tgW2, const float* __restrict__ tgb1, const float* __restrict__ tgb2,
    const float* __restrict__ eb1, const float* __restrict__ eb2, const float* __restrict__ eb3,
    const float* __restrict__ lns, const float* __restrict__ lnb,
    const float* __restrict__ sgW, const float* __restrict__ sgb,
    const float* __restrict__ twb1, const float* __restrict__ twb2,
    const float* __restrict__ twW3, const float* __restrict__ twb3,
    const u16* __restrict__ pk, float* __restrict__ out)
{
  __shared__ __align__(16) u16   cmfrag[4*8*64*8];   // 32768 B  [mt4][kt8][64][8]: mt0,1=t0 copy; mt2,3=t1 copy
  __shared__ __align__(16) u16   h1frag[4*4*64*8];   // 16384 B  [mt4][kt4][64][8]; alias accT f32[2][8][34]
  __shared__ __align__(16) u16   h2frag[4*2*64*8];   //  8192 B  [mt4][kt2][64][8]; alias aggfrag [8][64][8]
  __shared__ __align__(16) float fbuf[2*32*68];      // 17408 B  gh / e_pre per task; alias th1frag u16[2][2048]
  __shared__ __align__(16) float gwbuf[256];         //  1024 B  [2][32][4] softmax gate weights
  __shared__ __align__(16) float smallw[640];        //  2560 B  [2][320] tg_W2^T swizzled

  float* accT    = (float*)h1frag;   // [2][8][34] (gate phase only; dead before h1frag written)
  u16*   aggfrag = h2frag;           // [8 tiles][64][8]
  u16*   th1frag = (u16*)fbuf;       // [2][2048]

  const int tid  = threadIdx.x;
  const int lane = tid & 63;
  const int wid  = tid >> 6;       // wave 0..3
  const int r    = tid >> 3;       // row 0..31 (staging / softmax)
  const int q    = tid & 7;        // eighth of the 256-d feature
  const int rowBase = blockIdx.x * 32;
  const int mt_r = r >> 4, r15 = r & 15;
  const int rl   = (lane >> 4) * 4;   // C-layout row offset
  const int l15  = lane & 15;
  const int tkw  = wid >> 1;          // wave's task (0/1 within pair)
  const int chw  = wid & 1;           // wave's half-role
  const f32x4 fz = {0.f, 0.f, 0.f, 0.f};

  #pragma unroll 1
  for (int pair = 0; pair < 2; ++pair) {
    const int g = pair;
    const int tg0 = g*2 + tkw;       // wave's global task id

    // ---------- stage cm_pre (bf16) into BOTH task copies + tg_W2 for both tasks ----------
    {
      const float* zsrc = (q < 4)
        ? (zs + (size_t)(rowBase + r) * 128 + q * 32)
        : ((pair ? zg1 : zg0) + (size_t)(rowBase + r) * 128 + (q - 4) * 32);
      #pragma unroll
      for (int h = 0; h < 4; ++h) {
        float4 a = ((const float4*)zsrc)[2*h], b4 = ((const float4*)zsrc)[2*h+1];
        uint4 wv;
        wv.x = f2bf2(a.x, a.y);
        wv.y = f2bf2(a.z, a.w);
        wv.z = f2bf2(b4.x, b4.y);
        wv.w = f2bf2(b4.z, b4.w);
        *(uint4*)&cmfrag[((mt_r*8 + q)*64 + r15 + 16*h)*8] = wv;
        *(uint4*)&cmfrag[(((mt_r+2)*8 + q)*64 + r15 + 16*h)*8] = wv;
      }
    }
    #pragma unroll
    for (int tk = 0; tk < 2; ++tk) {
      int e = tid >> 6, c = tid & 63, half = c >> 5, cl = c & 31;
      smallw[tk*320 + (e*2 + half)*36 + cl] = tgW2[(g*2+tk)*256 + c*4 + e];
    }
    __syncthreads();   // A

    // prefetch fgB^T A-frags (first 4 of this wave's 8 mtiles)
    const u16* fgbp = pk + OFF_FGB + (tg0*16 + chw*8)*512 + lane*8;
    U4 afg[4];
    #pragma unroll
    for (int m4 = 0; m4 < 4; ++m4) afg[m4].u = *(const uint4*)(fgbp + m4*512);

    // ---------- gate step 1 (all 4 waves): accT[tk](8x32) = fgA^T @ cm_pre^T ----------
    {
      f32x4 d1 = fz;
      const u16* ap = pk + OFF_FGA + (tg0*8)*512 + lane*8;
      #pragma unroll
      for (int kt = 0; kt < 8; ++kt) {
        bf16x8 af = ld_frag(ap + kt*512);
        bf16x8 bf = ld_frag(&cmfrag[(((2*tkw + chw)*8 + kt)*64 + lane)*8]);
        d1 = mfma16(af, bf, d1);
      }
      if (rl < 8) {
        #pragma unroll
        for (int rr = 0; rr < 4; ++rr)
          accT[tkw*272 + (rl + rr)*34 + chw*16 + l15] = d1[rr];
      }
    }
    __syncthreads();   // A2

    // ---------- gate step 2 + in-place apply: logits = fgB^T @ accT; cm *= 2*sigmoid ----------
    {
      U4 b0u, b1u;
      if (lane < 16) {
        float v0[8], v1[8];
        #pragma unroll
        for (int i = 0; i < 8; ++i) {
          v0[i] = accT[tkw*272 + i*34 + l15];
          v1[i] = accT[tkw*272 + i*34 + 16 + l15];
        }
        b0u.u.x = f2bf2(v0[0], v0[1]); b0u.u.y = f2bf2(v0[2], v0[3]);
        b0u.u.z = f2bf2(v0[4], v0[5]); b0u.u.w = f2bf2(v0[6], v0[7]);
        b1u.u.x = f2bf2(v1[0], v1[1]); b1u.u.y = f2bf2(v1[2], v1[3]);
        b1u.u.z = f2bf2(v1[4], v1[5]); b1u.u.w = f2bf2(v1[6], v1[7]);
      } else {
        b0u.u = make_uint4(0, 0, 0, 0);
        b1u.u = make_uint4(0, 0, 0, 0);
      }
      const int i0 = rl & 7;              // 0 or 4
      const int hlo = rl >> 3;            // 0 or 1
      #pragma unroll
      for (int m8 = 0; m8 < 8; ++m8) {
        int mtile = chw*8 + m8;
        bf16x8 af = (m8 < 4) ? afg[m8].v : ld_frag(fgbp + m8*512);
        f32x4 d0 = mfma16(af, b0u.v, fz);
        f32x4 d1 = mfma16(af, b1u.v, fz);
        int ktc = mtile >> 1;
        int hh  = (mtile & 1)*2 + hlo;
        // rows 0-15 of this task -> mt = 2*tkw
        {
          u16* cp = &cmfrag[(((2*tkw)*8 + ktc)*64 + l15 + 16*hh)*8 + i0];
          u32 za = ((u32*)cp)[0], zb = ((u32*)cp)[1];
          float g0 = sig2(d0[0]), g1 = sig2(d0[1]), g2 = sig2(d0[2]), g3 = sig2(d0[3]);
          ((u32*)cp)[0] = f2bf2(bflo(za)*g0, bfhi(za)*g1);
          ((u32*)cp)[1] = f2bf2(bflo(zb)*g2, bfhi(zb)*g3);
        }
        // rows 16-31 -> mt = 2*tkw+1
        {
          u16* cp = &cmfrag[(((2*tkw + 1)*8 + ktc)*64 + l15 + 16*hh)*8 + i0];
          u32 za = ((u32*)cp)[0], zb = ((u32*)cp)[1];
          float g0 = sig2(d1[0]), g1 = sig2(d1[1]), g2 = sig2(d1[2]), g3 = sig2(d1[3]);
          ((u32*)cp)[0] = f2bf2(bflo(za)*g0, bfhi(za)*g1);
          ((u32*)cp)[1] = f2bf2(bflo(zb)*g2, bfhi(zb)*g3);
        }
      }
    }
    // prefetch tg_W1 kt0 for both of this wave's n-tiles (consumed right after A3)
    const u16* wp_tg = pk + OFF_TG + ((tg0*4 + chw*2)*8)*512 + lane*8;
    U4 tgp0, tgp1;
    tgp0.u = *(const uint4*)wp_tg;
    tgp1.u = *(const uint4*)(wp_tg + 4096);
    __syncthreads();   // A3

    // ---------- task gate layer1: wave (tk=wid>>1) computes n-tiles chw*2, chw*2+1 ----------
    {
      f32x4 accg[2][2] = { { fz, fz }, { fz, fz } };   // [mtl][nt2]
      #pragma unroll
      for (int kt = 0; kt < 8; ++kt) {
        bf16x8 b0 = (kt == 0) ? tgp0.v : ld_frag(wp_tg + kt*512);
        bf16x8 b1 = (kt == 0) ? tgp1.v : ld_frag(wp_tg + 4096 + kt*512);
        #pragma unroll
        for (int mtl = 0; mtl < 2; ++mtl) {
          bf16x8 a = ld_frag(&cmfrag[(((2*tkw + mtl)*8 + kt)*64 + lane)*8]);
          accg[mtl][0] = mfma16(a, b0, accg[mtl][0]);
          accg[mtl][1] = mfma16(a, b1, accg[mtl][1]);
        }
      }
      #pragma unroll
      for (int nt2 = 0; nt2 < 2; ++nt2) {
        int colg = (chw*2 + nt2)*16 + l15;
        float bias = tgb1[tg0*64 + colg];
        #pragma unroll
        for (int mtl = 0; mtl < 2; ++mtl)
          #pragma unroll
          for (int rr = 0; rr < 4; ++rr)
            fbuf[(tkw*32 + mtl*16 + rl + rr)*68 + colg] = swishf(accg[mtl][nt2][rr] + bias);
      }
    }
    __syncthreads();   // C

    // ---------- task gate layer2 + softmax, both tasks ----------
    #pragma unroll
    for (int tk = 0; tk < 2; ++tk) {
      int e = q & 3, half = q >> 2;
      float part = 0.f;
      #pragma unroll
      for (int cj = 0; cj < 8; ++cj) {
        float4 g4 = *(const float4*)&fbuf[(tk*32 + r)*68 + half*32 + cj*4];
        float4 w4 = *(const float4*)&smallw[tk*320 + (e*2 + half)*36 + cj*4];
        part += g4.x*w4.x + g4.y*w4.y + g4.z*w4.z + g4.w*w4.w;
      }
      part += __shfl_xor(part, 4);
      float logit = part + tgb2[(g*2+tk)*4 + e];
      float mx = fmaxf(logit, __shfl_xor(logit, 1));
      mx = fmaxf(mx, __shfl_xor(mx, 2));
      float ex = __expf(logit - mx);
      float sm = ex + __shfl_xor(ex, 1);
      sm += __shfl_xor(sm, 2);
      if (q < 4) gwbuf[tk*128 + r*4 + q] = ex / sm;
    }
    // NO barrier: gwbuf first read (LN el0) is >=3 barriers downstream; GEMM1 writes h1frag
    // (accT alias dead since A3).

    // ---------- expert loop: M=64 (both tasks) ----------
    float agg[16];
    #pragma unroll
    for (int c = 0; c < 16; ++c) agg[c] = 0.f;

    const int mL  = tid >> 2;        // LN row 0..63
    const int qc  = tid & 3;         // LN col quarter (16 cols)
    const int tkL = mL >> 5, mrL = mL & 31;

    #pragma unroll 1
    for (int el = 0; el < 4; ++el) {
      const int ei = (el < 2) ? el : (el + 2*g);

      // GEMM1: cm(64x256) @ W1(256x128); wave owns n-tiles 2w,2w+1; 2 passes over task halves
      const u16* w1p = pk + ((ei*8 + 2*wid)*8)*512 + lane*8;
      #pragma unroll 1
      for (int pass = 0; pass < 2; ++pass) {
        f32x4 acc1[2][2] = { { fz, fz }, { fz, fz } };   // [mtl][nn]
        #pragma unroll
        for (int kt = 0; kt < 8; ++kt) {
          bf16x8 b0 = ld_frag(w1p + kt*512);
          bf16x8 b1 = ld_frag(w1p + 4096 + kt*512);
          #pragma unroll
          for (int mtl = 0; mtl < 2; ++mtl) {
            bf16x8 a = ld_frag(&cmfrag[(((pass*2 + mtl)*8 + kt)*64 + lane)*8]);
            acc1[mtl][0] = mfma16(a, b0, acc1[mtl][0]);
            acc1[mtl][1] = mfma16(a, b1, acc1[mtl][1]);
          }
        }
        #pragma unroll
        for (int nn = 0; nn < 2; ++nn) {
          int col = (2*wid + nn)*16 + l15;
          float bias = eb1[ei*128 + col];
          int kt2 = col >> 5, h2 = (col >> 3) & 3, i2 = col & 7;
          #pragma unroll
          for (int mtl = 0; mtl < 2; ++mtl)
            #pragma unroll
            for (int rr = 0; rr < 4; ++rr)
              h1frag[(((pass*2 + mtl)*4 + kt2)*64 + rl + rr + 16*h2)*8 + i2] =
                  f2bf(swishf(acc1[mtl][nn][rr] + bias));
        }
      }
      // prefetch W2 kt0,1 (consumed right after E1)
      const u16* w2p = pk + OFF_W2 + ((ei*4 + wid)*4)*512 + lane*8;
      U4 w2f0, w2f1;
      w2f0.u = *(const uint4*)w2p;
      w2f1.u = *(const uint4*)(w2p + 512);
      __syncthreads();  // E1

      // GEMM2: h1(64x128) @ W2(128x64); wave owns n-tile w
      f32x4 acc2[4] = { fz, fz, fz, fz };
      #pragma unroll
      for (int kt = 0; kt < 4; ++kt) {
        bf16x8 b0 = (kt == 0) ? w2f0.v : (kt == 1) ? w2f1.v : ld_frag(w2p + kt*512);
        #pragma unroll
        for (int mt = 0; mt < 4; ++mt) {
          bf16x8 a = ld_frag(&h1frag[((mt*4 + kt)*64 + lane)*8]);
          acc2[mt] = mfma16(a, b0, acc2[mt]);
        }
      }
      // prefetch W3 both frags (consumed right after E2)
      const u16* w3p = pk + OFF_W3 + ((ei*4 + wid)*2)*512 + lane*8;
      U4 w3f0, w3f1;
      w3f0.u = *(const uint4*)w3p;
      w3f1.u = *(const uint4*)(w3p + 512);
      {
        int col = wid*16 + l15;
        float bias = eb2[ei*64 + col];
        int kt2 = col >> 5, h2 = (col >> 3) & 3, i2 = col & 7;
        #pragma unroll
        for (int mt = 0; mt < 4; ++mt)
          #pragma unroll
          for (int rr = 0; rr < 4; ++rr)
            h2frag[((mt*2 + kt2)*64 + rl + rr + 16*h2)*8 + i2] = f2bf(swishf(acc2[mt][rr] + bias));
      }
      __syncthreads();  // E2

      // GEMM3: h2(64x64) @ W3(64x64) -> e_pre into fbuf (per-task halves)
      f32x4 acc3[4] = { fz, fz, fz, fz };
      #pragma unroll
      for (int kt = 0; kt < 2; ++kt) {
        bf16x8 b0 = (kt == 0) ? w3f0.v : w3f1.v;
        #pragma unroll
        for (int mt = 0; mt < 4; ++mt) {
          bf16x8 a = ld_frag(&h2frag[((mt*2 + kt)*64 + lane)*8]);
          acc3[mt] = mfma16(a, b0, acc3[mt]);
        }
      }
      {
        int col = wid*16 + l15;
        float bias = eb3[ei*64 + col];
        #pragma unroll
        for (int mt = 0; mt < 4; ++mt)
          #pragma unroll
          for (int rr = 0; rr < 4; ++rr) {
            int m = mt*16 + rl + rr;
            fbuf[((m >> 5)*32 + (m & 31))*68 + col] = acc3[mt][rr] + bias;
          }
      }
      __syncthreads();  // E3

      // LayerNorm + self-gate diag + weighted aggregate (thread: row mL, 16 cols qc*16..)
      {
        float v[16];
        #pragma unroll
        for (int cc = 0; cc < 4; ++cc) {
          float4 f = *(const float4*)&fbuf[(tkL*32 + mrL)*68 + qc*16 + cc*4];
          v[cc*4+0] = f.x; v[cc*4+1] = f.y; v[cc*4+2] = f.z; v[cc*4+3] = f.w;
        }
        float s1 = 0.f;
        #pragma unroll
        for (int c = 0; c < 16; ++c) s1 += v[c];
        s1 += __shfl_xor(s1, 1); s1 += __shfl_xor(s1, 2);
        float mu = s1 * (1.f/64.f);
        float s2 = 0.f;
        #pragma unroll
        for (int c = 0; c < 16; ++c) { float d = v[c] - mu; s2 += d*d; }
        s2 += __shfl_xor(s2, 1); s2 += __shfl_xor(s2, 2);
        float rs = rsqrtf(s2 * (1.f/64.f) + 1e-5f);
        const int tgL = g*2 + tkL;
        const float* lsp = lns + ei*64 + qc*16;
        const float* lbp = lnb + ei*64 + qc*16;
        const float* sgp = sgW + (tgL*64 + qc*16)*4 + el;
        float swp = 0.f;
        #pragma unroll
        for (int c = 0; c < 16; ++c) {
          float eh = (v[c] - mu) * rs * lsp[c] + lbp[c];
          v[c] = eh;
          swp += eh * sgp[c*4];
        }
        swp += __shfl_xor(swp, 1); swp += __shfl_xor(swp, 2);
        swp += sgb[tgL*4 + el];
        float fac = swp * gwbuf[tkL*128 + mrL*4 + el];
        #pragma unroll
        for (int c = 0; c < 16; ++c) agg[c] += v[c] * fac;
      }
      // no trailing barrier: next GEMM1 writes h1frag (disjoint from fbuf/gwbuf); E1 orders.
    }  // expert loop

    // ---------- tower: agg(64x64) -> T1 (per task 32x64) -> T2 (32x32) -> out ----------
    {
      // write agg as A-frags: thread row mL, feats qc*16+0..15 (2 b128)
      #pragma unroll
      for (int jh = 0; jh < 2; ++jh) {
        uint4 wv;
        wv.x = f2bf2(agg[jh*8+0], agg[jh*8+1]);
        wv.y = f2bf2(agg[jh*8+2], agg[jh*8+3]);
        wv.z = f2bf2(agg[jh*8+4], agg[jh*8+5]);
        wv.w = f2bf2(agg[jh*8+6], agg[jh*8+7]);
        int tile = (mL >> 4)*2 + (qc >> 1);
        int slot = (mL & 15) + 16*((qc & 1)*2 + jh);
        *(uint4*)&aggfrag[(tile*64 + slot)*8] = wv;
      }
    }
    // prefetch tw_W1 kt0 for both of this wave's n-tiles
    const u16* tw1b = pk + OFF_TW1 + ((tg0*4 + chw*2)*2)*512 + lane*8;
    U4 t1f0, t1f1;
    t1f0.u = *(const uint4*)tw1b;
    t1f1.u = *(const uint4*)(tw1b + 1024);
    __syncthreads();  // F

    // T1: wave (task tkw) computes n-tiles chw*2, chw*2+1 of its task's 64 cols
    {
      f32x4 at1[2][2] = { { fz, fz }, { fz, fz } };   // [mtl][nt2]
      #pragma unroll
      for (int kt = 0; kt < 2; ++kt) {
        bf16x8 b0 = (kt == 0) ? t1f0.v : ld_frag(tw1b + kt*512);
        bf16x8 b1 = (kt == 0) ? t1f1.v : ld_frag(tw1b + 1024 + kt*512);
        #pragma unroll
        for (int mtl = 0; mtl < 2; ++mtl) {
          bf16x8 a = ld_frag(&aggfrag[(((2*tkw + mtl)*2 + kt)*64 + lane)*8]);
          at1[mtl][0] = mfma16(a, b0, at1[mtl][0]);
          at1[mtl][1] = mfma16(a, b1, at1[mtl][1]);
        }
      }
      #pragma unroll
      for (int nt2 = 0; nt2 < 2; ++nt2) {
        int colT = (chw*2 + nt2)*16 + l15;
        float bias = twb1[tg0*64 + colT];
        int ktT = colT >> 5, hT = (colT >> 3) & 3, iT = colT & 7;
        #pragma unroll
        for (int mtl = 0; mtl < 2; ++mtl)
          #pragma unroll
          for (int rr = 0; rr < 4; ++rr)
            th1frag[tkw*2048 + ((mtl*2 + ktT)*64 + rl + rr + 16*hT)*8 + iT] =
                f2bf(swishf(at1[mtl][nt2][rr] + bias));
      }
    }
    __syncthreads();  // G

    // T2 + output: wave w<2 handles task w entirely (both 16-col tiles), writes out.
    if (wid < 2) {
      const int tg = g*2 + wid;
      f32x4 at2[2][2] = { { fz, fz }, { fz, fz } };   // [nt][mtl]
      const u16* tw2p = pk + OFF_TW2 + (tg*2*2)*512 + lane*8;
      #pragma unroll
      for (int kt = 0; kt < 2; ++kt) {
        bf16x8 b0 = ld_frag(tw2p + kt*512);
        bf16x8 b1 = ld_frag(tw2p + 1024 + kt*512);
        #pragma unroll
        for (int mtl = 0; mtl < 2; ++mtl) {
          bf16x8 a = ld_frag(&th1frag[wid*2048 + ((mtl*2 + kt)*64 + lane)*8]);
          at2[0][mtl] = mfma16(a, b0, at2[0][mtl]);
          at2[1][mtl] = mfma16(a, b1, at2[1][mtl]);
        }
      }
      float pxs[8];
      #pragma unroll
      for (int nt = 0; nt < 2; ++nt) {
        int colU = nt*16 + l15;
        float b2  = twb2[tg*32 + colU];
        float w3v = twW3[tg*32 + colU];
        #pragma unroll
        for (int mtl = 0; mtl < 2; ++mtl)
          #pragma unroll
          for (int rr = 0; rr < 4; ++rr) {
            float val = swishf(at2[nt][mtl][rr] + b2) * w3v;
            if (nt == 0) pxs[mtl*4 + rr] = val;
            else         pxs[mtl*4 + rr] += val;
          }
      }
      #pragma unroll
      for (int k = 0; k < 8; ++k) {
        pxs[k] += __shfl_xor(pxs[k], 1);
        pxs[k] += __shfl_xor(pxs[k], 2);
        pxs[k] += __shfl_xor(pxs[k], 4);
        pxs[k] += __shfl_xor(pxs[k], 8);
      }
      if (l15 == 0) {
        float b3 = twb3[tg];
        #pragma unroll
        for (int mtl = 0; mtl < 2; ++mtl)
          #pragma unroll
          for (int rr = 0; rr < 4; ++rr) {
            int row = mtl*16 + rl + rr;
            float x = pxs[mtl*4 + rr] + b3;
            out[(size_t)(rowBase + row)*4 + tg] = 1.f / (1.f + __expf(-x));
          }
      }
    }
    // no trailing barrier: next pair's staging writes cmfrag/smallw whose last readers
    // (GEMM1 el3 / softmax) are many barriers back; th1frag (fbuf) readers here are
    // waves 0,1 only, and next writes to that region (tg1 epilogue) are behind A/A2/A3.
  }
}

extern "C" void kernel_launch(void* const* d_in, const int* in_sizes, int n_in,
                              void* d_out, int out_size, void* d_ws, size_t ws_size,
                              hipStream_t stream)
{
  (void)in_sizes; (void)n_in; (void)out_size; (void)ws_size;
  const float* zs   = (const float*)d_in[0];
  const float* zg0  = (const float*)d_in[1];
  const float* zg1  = (const float*)d_in[2];
  // d_in[3] = v : unused by the reference
  const float* eW1  = (const float*)d_in[4];
  const float* eb1  = (const float*)d_in[5];
  const float* eW2  = (const float*)d_in[6];
  const float* eb2  = (const float*)d_in[7];
  const float* eW3  = (const float*)d_in[8];
  const float* eb3  = (const float*)d_in[9];
  const float* lns  = (const float*)d_in[10];
  const float* lnb  = (const float*)d_in[11];
  const float* fgA  = (const float*)d_in[12];
  const float* fgB  = (const float*)d_in[13];
  const float* tgW1 = (const float*)d_in[14];
  const float* tgb1 = (const float*)d_in[15];
  const float* tgW2 = (const float*)d_in[16];
  const float* tgb2 = (const float*)d_in[17];
  const float* sgW  = (const float*)d_in[18];
  const float* sgb  = (const float*)d_in[19];
  const float* twW1 = (const float*)d_in[20];
  const float* twb1 = (const float*)d_in[21];
  const float* twW2 = (const float*)d_in[22];
  const float* twb2 = (const float*)d_in[23];
  const float* twW3 = (const float*)d_in[24];
  const float* twb3 = (const float*)d_in[25];

  u16* pkw = (u16*)d_ws;          // needs 819200 B
  float* outp = (float*)d_out;

  prep_pack<<<(NPACK + 255)/256, 256, 0, stream>>>(eW1, eW2, eW3, tgW1, twW1, twW2, fgA, fgB, pkw);
  home_main<<<65536/32, 256, 0, stream>>>(zs, zg0, zg1, tgW2, tgb1, tgb2,
      eb1, eb2, eb3, lns, lnb, sgW, sgb, twb1, twb2, twW3, twb3,
      pkw, outp);
}

// Round 15
// 281.951 us; speedup vs baseline: 2.1104x; 1.2262x over previous
//
#include <hip/hip_runtime.h>

typedef unsigned short u16;
typedef unsigned int   u32;
typedef __bf16 bf16x8 __attribute__((ext_vector_type(8)));
typedef float  f32x4  __attribute__((ext_vector_type(4)));

// packed-weight regions (bf16 elements) in d_ws
#define OFF_W2  196608
#define OFF_W3  245760
#define OFF_TG  270336
#define OFF_TW1 335872
#define OFF_TW2 352256
#define OFF_FGA 360448
#define OFF_FGB 376832
#define NPACK   409600

// native f32->bf16 (RNE): v_cvt_pk_bf16_f32
__device__ __forceinline__ u16 f2bf(float f) {
  union { __bf16 b; u16 u; } cv;
  cv.b = (__bf16)f;
  return cv.u;
}
__device__ __forceinline__ u32 f2bf2(float lo, float hi) {
  return (u32)f2bf(lo) | ((u32)f2bf(hi) << 16);
}
__device__ __forceinline__ float bflo(u32 p) { return __uint_as_float(p << 16); }
__device__ __forceinline__ float bfhi(u32 p) { return __uint_as_float(p & 0xffff0000u); }

union U4 { uint4 u; bf16x8 v; };
__device__ __forceinline__ bf16x8 ld_frag(const u16* p) {
  U4 t; t.u = *(const uint4*)p; return t.v;
}
__device__ __forceinline__ f32x4 mfma16(bf16x8 a, bf16x8 b, f32x4 c) {
  return __builtin_amdgcn_mfma_f32_16x16x32_bf16(a, b, c, 0, 0, 0);
}
// r15: single-instruction v_rcp_f32 (~1 ULP) instead of IEEE div (div_scale/div_fmas/div_fixup,
// ~9 VALU ops). ~540 divides/thread -> ~4800 VALU instrs saved. Error invisible under bf16.
__device__ __forceinline__ float fastrcp(float x) { return __builtin_amdgcn_rcpf(x); }
__device__ __forceinline__ float swishf(float x) { return x * fastrcp(1.f + __expf(-x)); }
__device__ __forceinline__ float sig2(float x) { return 2.f * fastrcp(1.f + __expf(-x)); }
__device__ __forceinline__ float sig1(float x) { return fastrcp(1.f + __expf(-x)); }

// ---------------- weight repack: f32 row-major -> bf16 fragment order (unchanged) ----------------
__global__ __launch_bounds__(256) void prep_pack(
    const float* __restrict__ eW1, const float* __restrict__ eW2,
    const float* __restrict__ eW3, const float* __restrict__ tgW1,
    const float* __restrict__ twW1, const float* __restrict__ twW2,
    const float* __restrict__ fgA, const float* __restrict__ fgB,
    u16* __restrict__ pk)
{
  int idx = blockIdx.x * 256 + threadIdx.x;
  if (idx >= NPACK) return;
  float v;
  if (idx < OFF_W2) {                 // exp_W1: [6][nt:8][kt:8][64][8]
    int i = idx & 7, lane = (idx >> 3) & 63, kt = (idx >> 9) & 7, nt = (idx >> 12) & 7, e = idx >> 15;
    int k = kt*32 + (lane>>4)*8 + i, n = nt*16 + (lane & 15);
    v = eW1[(e*256 + k)*128 + n];
  } else if (idx < OFF_W3) {          // exp_W2: [6][nt:4][kt:4][64][8]
    int j = idx - OFF_W2;
    int i = j & 7, lane = (j >> 3) & 63, kt = (j >> 9) & 3, nt = (j >> 11) & 3, e = j >> 13;
    int k = kt*32 + (lane>>4)*8 + i, n = nt*16 + (lane & 15);
    v = eW2[(e*128 + k)*64 + n];
  } else if (idx < OFF_TG) {          // exp_W3: [6][nt:4][kt:2][64][8]
    int j = idx - OFF_W3;
    int i = j & 7, lane = (j >> 3) & 63, kt = (j >> 9) & 1, nt = (j >> 10) & 3, e = j >> 12;
    int k = kt*32 + (lane>>4)*8 + i, n = nt*16 + (lane & 15);
    v = eW3[(e*64 + k)*64 + n];
  } else if (idx < OFF_TW1) {         // tg_W1: [4][nt:4][kt:8][64][8]
    int j = idx - OFF_TG;
    int i = j & 7, lane = (j >> 3) & 63, kt = (j >> 9) & 7, nt = (j >> 12) & 3, t = j >> 14;
    int k = kt*32 + (lane>>4)*8 + i, n = nt*16 + (lane & 15);
    v = tgW1[(t*256 + k)*64 + n];
  } else if (idx < OFF_TW2) {         // tw_W1: [4][nt:4][kt:2][64][8]
    int j = idx - OFF_TW1;
    int i = j & 7, lane = (j >> 3) & 63, kt = (j >> 9) & 1, nt = (j >> 10) & 3, t = j >> 12;
    int k = kt*32 + (lane>>4)*8 + i, n = nt*16 + (lane & 15);
    v = twW1[(t*64 + k)*64 + n];
  } else if (idx < OFF_FGA) {         // tw_W2: [4][nt:2][kt:2][64][8]
    int j = idx - OFF_TW2;
    int i = j & 7, lane = (j >> 3) & 63, kt = (j >> 9) & 1, nt = (j >> 10) & 1, t = j >> 11;
    int k = kt*32 + (lane>>4)*8 + i, n = nt*16 + (lane & 15);
    v = twW2[(t*64 + k)*32 + n];
  } else if (idx < OFF_FGB) {         // fgA^T A-frags: [4][kt:8][64][8]
    int j = idx - OFF_FGA;
    int i = j & 7, lane = (j >> 3) & 63, kt = (j >> 9) & 7, t = j >> 12;
    int m = lane & 15, k = kt*32 + (lane>>4)*8 + i;
    v = (m < 8) ? fgA[(t*256 + k)*8 + m] : 0.f;
  } else {                            // fgB^T A-frags: [4][mtile:16][64][8]
    int j = idx - OFF_FGB;
    int i = j & 7, lane = (j >> 3) & 63, mtl = (j >> 9) & 15, t = j >> 13;
    int m = mtl*16 + (lane & 15), kr = (lane>>4)*8 + i;
    v = (kr < 8) ? fgB[t*2048 + kr*256 + m] : 0.f;
  }
  pk[idx] = f2bf(v);
}

// ---------------- fused main kernel: 32 batch rows/block, M=64 task-pair-batched expert chain ----------------
// r15 = r11/r14 structure VERBATIM + one leaf substitution: all sigmoid/swish/softmax divisions
// -> v_rcp_f32 (see fastrcp above). No structural or register-pressure change.
// Ledger: r11/r14 = 346 us, VGPR 120, occ 21.9%. r12 (VGPR 148) / r13 (VGPR 144) -> ~590 us:
// any structural edit to the expert loop risks the 128-reg/2-block cliff. VGPR tripwire: 120.
__global__ __launch_bounds__(256, 3) void home_main(
    const float* __restrict__ zs, const float* __restrict__ zg0, const float* __restrict__ zg1,
    const float* __restrict__ tgW2, const float* __restrict__ tgb1, const float* __restrict__ tgb2,
    const float* __restrict__ eb1, const float* __restrict__ eb2, const float* __restrict__ eb3,
    const float* __restrict__ lns, const float* __restrict__ lnb,
    const float* __restrict__ sgW, const float* __restrict__ sgb,
    const float* __restrict__ twb1, const float* __restrict__ twb2,
    const float* __restrict__ twW3, const float* __restrict__ twb3,
    const u16* __restrict__ pk, float* __restrict__ out)
{
  __shared__ __align__(16) u16   cmfrag[4*8*64*8];   // 32768 B  [mt4][kt8][64][8]: mt0,1=t0 copy; mt2,3=t1 copy
  __shared__ __align__(16) u16   h1frag[4*4*64*8];   // 16384 B  [mt4][kt4][64][8]; alias accT f32[2][8][34]
  __shared__ __align__(16) u16   h2frag[4*2*64*8];   //  8192 B  [mt4][kt2][64][8]; alias aggfrag [8][64][8]
  __shared__ __align__(16) float fbuf[2*32*68];      // 17408 B  gh / e_pre per task; alias th1frag u16[2][2048]
  __shared__ __align__(16) float gwbuf[256];         //  1024 B  [2][32][4] softmax gate weights
  __shared__ __align__(16) float smallw[640];        //  2560 B  [2][320] tg_W2^T swizzled

  float* accT    = (float*)h1frag;   // [2][8][34] (gate phase only; dead before h1frag written)
  u16*   aggfrag = h2frag;           // [8 tiles][64][8]
  u16*   th1frag = (u16*)fbuf;       // [2][2048]

  const int tid  = threadIdx.x;
  const int lane = tid & 63;
  const int wid  = tid >> 6;       // wave 0..3
  const int r    = tid >> 3;       // row 0..31 (staging / softmax)
  const int q    = tid & 7;        // eighth of the 256-d feature
  const int rowBase = blockIdx.x * 32;
  const int mt_r = r >> 4, r15 = r & 15;
  const int rl   = (lane >> 4) * 4;   // C-layout row offset
  const int l15  = lane & 15;
  const int tkw  = wid >> 1;          // wave's task (0/1 within pair)
  const int chw  = wid & 1;           // wave's half-role
  const f32x4 fz = {0.f, 0.f, 0.f, 0.f};

  #pragma unroll 1
  for (int pair = 0; pair < 2; ++pair) {
    const int g = pair;
    const int tg0 = g*2 + tkw;       // wave's global task id

    // ---------- stage cm_pre (bf16) into BOTH task copies + tg_W2 for both tasks ----------
    {
      const float* zsrc = (q < 4)
        ? (zs + (size_t)(rowBase + r) * 128 + q * 32)
        : ((pair ? zg1 : zg0) + (size_t)(rowBase + r) * 128 + (q - 4) * 32);
      #pragma unroll
      for (int h = 0; h < 4; ++h) {
        float4 a = ((const float4*)zsrc)[2*h], b4 = ((const float4*)zsrc)[2*h+1];
        uint4 wv;
        wv.x = f2bf2(a.x, a.y);
        wv.y = f2bf2(a.z, a.w);
        wv.z = f2bf2(b4.x, b4.y);
        wv.w = f2bf2(b4.z, b4.w);
        *(uint4*)&cmfrag[((mt_r*8 + q)*64 + r15 + 16*h)*8] = wv;
        *(uint4*)&cmfrag[(((mt_r+2)*8 + q)*64 + r15 + 16*h)*8] = wv;
      }
    }
    #pragma unroll
    for (int tk = 0; tk < 2; ++tk) {
      int e = tid >> 6, c = tid & 63, half = c >> 5, cl = c & 31;
      smallw[tk*320 + (e*2 + half)*36 + cl] = tgW2[(g*2+tk)*256 + c*4 + e];
    }
    __syncthreads();   // A

    // prefetch fgB^T A-frags (first 4 of this wave's 8 mtiles)
    const u16* fgbp = pk + OFF_FGB + (tg0*16 + chw*8)*512 + lane*8;
    U4 afg[4];
    #pragma unroll
    for (int m4 = 0; m4 < 4; ++m4) afg[m4].u = *(const uint4*)(fgbp + m4*512);

    // ---------- gate step 1 (all 4 waves): accT[tk](8x32) = fgA^T @ cm_pre^T ----------
    {
      f32x4 d1 = fz;
      const u16* ap = pk + OFF_FGA + (tg0*8)*512 + lane*8;
      #pragma unroll
      for (int kt = 0; kt < 8; ++kt) {
        bf16x8 af = ld_frag(ap + kt*512);
        bf16x8 bf = ld_frag(&cmfrag[(((2*tkw + chw)*8 + kt)*64 + lane)*8]);
        d1 = mfma16(af, bf, d1);
      }
      if (rl < 8) {
        #pragma unroll
        for (int rr = 0; rr < 4; ++rr)
          accT[tkw*272 + (rl + rr)*34 + chw*16 + l15] = d1[rr];
      }
    }
    __syncthreads();   // A2

    // ---------- gate step 2 + in-place apply: logits = fgB^T @ accT; cm *= 2*sigmoid ----------
    {
      U4 b0u, b1u;
      if (lane < 16) {
        float v0[8], v1[8];
        #pragma unroll
        for (int i = 0; i < 8; ++i) {
          v0[i] = accT[tkw*272 + i*34 + l15];
          v1[i] = accT[tkw*272 + i*34 + 16 + l15];
        }
        b0u.u.x = f2bf2(v0[0], v0[1]); b0u.u.y = f2bf2(v0[2], v0[3]);
        b0u.u.z = f2bf2(v0[4], v0[5]); b0u.u.w = f2bf2(v0[6], v0[7]);
        b1u.u.x = f2bf2(v1[0], v1[1]); b1u.u.y = f2bf2(v1[2], v1[3]);
        b1u.u.z = f2bf2(v1[4], v1[5]); b1u.u.w = f2bf2(v1[6], v1[7]);
      } else {
        b0u.u = make_uint4(0, 0, 0, 0);
        b1u.u = make_uint4(0, 0, 0, 0);
      }
      const int i0 = rl & 7;              // 0 or 4
      const int hlo = rl >> 3;            // 0 or 1
      #pragma unroll
      for (int m8 = 0; m8 < 8; ++m8) {
        int mtile = chw*8 + m8;
        bf16x8 af = (m8 < 4) ? afg[m8].v : ld_frag(fgbp + m8*512);
        f32x4 d0 = mfma16(af, b0u.v, fz);
        f32x4 d1 = mfma16(af, b1u.v, fz);
        int ktc = mtile >> 1;
        int hh  = (mtile & 1)*2 + hlo;
        // rows 0-15 of this task -> mt = 2*tkw
        {
          u16* cp = &cmfrag[(((2*tkw)*8 + ktc)*64 + l15 + 16*hh)*8 + i0];
          u32 za = ((u32*)cp)[0], zb = ((u32*)cp)[1];
          float g0 = sig2(d0[0]), g1 = sig2(d0[1]), g2 = sig2(d0[2]), g3 = sig2(d0[3]);
          ((u32*)cp)[0] = f2bf2(bflo(za)*g0, bfhi(za)*g1);
          ((u32*)cp)[1] = f2bf2(bflo(zb)*g2, bfhi(zb)*g3);
        }
        // rows 16-31 -> mt = 2*tkw+1
        {
          u16* cp = &cmfrag[(((2*tkw + 1)*8 + ktc)*64 + l15 + 16*hh)*8 + i0];
          u32 za = ((u32*)cp)[0], zb = ((u32*)cp)[1];
          float g0 = sig2(d1[0]), g1 = sig2(d1[1]), g2 = sig2(d1[2]), g3 = sig2(d1[3]);
          ((u32*)cp)[0] = f2bf2(bflo(za)*g0, bfhi(za)*g1);
          ((u32*)cp)[1] = f2bf2(bflo(zb)*g2, bfhi(zb)*g3);
        }
      }
    }
    // prefetch tg_W1 kt0 for both of this wave's n-tiles (consumed right after A3)
    const u16* wp_tg = pk + OFF_TG + ((tg0*4 + chw*2)*8)*512 + lane*8;
    U4 tgp0, tgp1;
    tgp0.u = *(const uint4*)wp_tg;
    tgp1.u = *(const uint4*)(wp_tg + 4096);
    __syncthreads();   // A3

    // ---------- task gate layer1: wave (tk=wid>>1) computes n-tiles chw*2, chw*2+1 ----------
    {
      f32x4 accg[2][2] = { { fz, fz }, { fz, fz } };   // [mtl][nt2]
      #pragma unroll
      for (int kt = 0; kt < 8; ++kt) {
        bf16x8 b0 = (kt == 0) ? tgp0.v : ld_frag(wp_tg + kt*512);
        bf16x8 b1 = (kt == 0) ? tgp1.v : ld_frag(wp_tg + 4096 + kt*512);
        #pragma unroll
        for (int mtl = 0; mtl < 2; ++mtl) {
          bf16x8 a = ld_frag(&cmfrag[(((2*tkw + mtl)*8 + kt)*64 + lane)*8]);
          accg[mtl][0] = mfma16(a, b0, accg[mtl][0]);
          accg[mtl][1] = mfma16(a, b1, accg[mtl][1]);
        }
      }
      #pragma unroll
      for (int nt2 = 0; nt2 < 2; ++nt2) {
        int colg = (chw*2 + nt2)*16 + l15;
        float bias = tgb1[tg0*64 + colg];
        #pragma unroll
        for (int mtl = 0; mtl < 2; ++mtl)
          #pragma unroll
          for (int rr = 0; rr < 4; ++rr)
            fbuf[(tkw*32 + mtl*16 + rl + rr)*68 + colg] = swishf(accg[mtl][nt2][rr] + bias);
      }
    }
    __syncthreads();   // C

    // ---------- task gate layer2 + softmax, both tasks ----------
    #pragma unroll
    for (int tk = 0; tk < 2; ++tk) {
      int e = q & 3, half = q >> 2;
      float part = 0.f;
      #pragma unroll
      for (int cj = 0; cj < 8; ++cj) {
        float4 g4 = *(const float4*)&fbuf[(tk*32 + r)*68 + half*32 + cj*4];
        float4 w4 = *(const float4*)&smallw[tk*320 + (e*2 + half)*36 + cj*4];
        part += g4.x*w4.x + g4.y*w4.y + g4.z*w4.z + g4.w*w4.w;
      }
      part += __shfl_xor(part, 4);
      float logit = part + tgb2[(g*2+tk)*4 + e];
      float mx = fmaxf(logit, __shfl_xor(logit, 1));
      mx = fmaxf(mx, __shfl_xor(mx, 2));
      float ex = __expf(logit - mx);
      float sm = ex + __shfl_xor(ex, 1);
      sm += __shfl_xor(sm, 2);
      if (q < 4) gwbuf[tk*128 + r*4 + q] = ex * fastrcp(sm);
    }
    // NO barrier: gwbuf first read (LN el0) is >=3 barriers downstream; GEMM1 writes h1frag
    // (accT alias dead since A3).

    // ---------- expert loop: M=64 (both tasks) ----------
    float agg[16];
    #pragma unroll
    for (int c = 0; c < 16; ++c) agg[c] = 0.f;

    const int mL  = tid >> 2;        // LN row 0..63
    const int qc  = tid & 3;         // LN col quarter (16 cols)
    const int tkL = mL >> 5, mrL = mL & 31;

    #pragma unroll 1
    for (int el = 0; el < 4; ++el) {
      const int ei = (el < 2) ? el : (el + 2*g);

      // GEMM1: cm(64x256) @ W1(256x128); wave owns n-tiles 2w,2w+1; 2 passes over task halves
      const u16* w1p = pk + ((ei*8 + 2*wid)*8)*512 + lane*8;
      #pragma unroll 1
      for (int pass = 0; pass < 2; ++pass) {
        f32x4 acc1[2][2] = { { fz, fz }, { fz, fz } };   // [mtl][nn]
        #pragma unroll
        for (int kt = 0; kt < 8; ++kt) {
          bf16x8 b0 = ld_frag(w1p + kt*512);
          bf16x8 b1 = ld_frag(w1p + 4096 + kt*512);
          #pragma unroll
          for (int mtl = 0; mtl < 2; ++mtl) {
            bf16x8 a = ld_frag(&cmfrag[(((pass*2 + mtl)*8 + kt)*64 + lane)*8]);
            acc1[mtl][0] = mfma16(a, b0, acc1[mtl][0]);
            acc1[mtl][1] = mfma16(a, b1, acc1[mtl][1]);
          }
        }
        #pragma unroll
        for (int nn = 0; nn < 2; ++nn) {
          int col = (2*wid + nn)*16 + l15;
          float bias = eb1[ei*128 + col];
          int kt2 = col >> 5, h2 = (col >> 3) & 3, i2 = col & 7;
          #pragma unroll
          for (int mtl = 0; mtl < 2; ++mtl)
            #pragma unroll
            for (int rr = 0; rr < 4; ++rr)
              h1frag[(((pass*2 + mtl)*4 + kt2)*64 + rl + rr + 16*h2)*8 + i2] =
                  f2bf(swishf(acc1[mtl][nn][rr] + bias));
        }
      }
      // prefetch W2 kt0,1 (consumed right after E1)
      const u16* w2p = pk + OFF_W2 + ((ei*4 + wid)*4)*512 + lane*8;
      U4 w2f0, w2f1;
      w2f0.u = *(const uint4*)w2p;
      w2f1.u = *(const uint4*)(w2p + 512);
      __syncthreads();  // E1

      // GEMM2: h1(64x128) @ W2(128x64); wave owns n-tile w
      f32x4 acc2[4] = { fz, fz, fz, fz };
      #pragma unroll
      for (int kt = 0; kt < 4; ++kt) {
        bf16x8 b0 = (kt == 0) ? w2f0.v : (kt == 1) ? w2f1.v : ld_frag(w2p + kt*512);
        #pragma unroll
        for (int mt = 0; mt < 4; ++mt) {
          bf16x8 a = ld_frag(&h1frag[((mt*4 + kt)*64 + lane)*8]);
          acc2[mt] = mfma16(a, b0, acc2[mt]);
        }
      }
      // prefetch W3 both frags (consumed right after E2)
      const u16* w3p = pk + OFF_W3 + ((ei*4 + wid)*2)*512 + lane*8;
      U4 w3f0, w3f1;
      w3f0.u = *(const uint4*)w3p;
      w3f1.u = *(const uint4*)(w3p + 512);
      {
        int col = wid*16 + l15;
        float bias = eb2[ei*64 + col];
        int kt2 = col >> 5, h2 = (col >> 3) & 3, i2 = col & 7;
        #pragma unroll
        for (int mt = 0; mt < 4; ++mt)
          #pragma unroll
          for (int rr = 0; rr < 4; ++rr)
            h2frag[((mt*2 + kt2)*64 + rl + rr + 16*h2)*8 + i2] = f2bf(swishf(acc2[mt][rr] + bias));
      }
      __syncthreads();  // E2

      // GEMM3: h2(64x64) @ W3(64x64) -> e_pre into fbuf (per-task halves)
      f32x4 acc3[4] = { fz, fz, fz, fz };
      #pragma unroll
      for (int kt = 0; kt < 2; ++kt) {
        bf16x8 b0 = (kt == 0) ? w3f0.v : w3f1.v;
        #pragma unroll
        for (int mt = 0; mt < 4; ++mt) {
          bf16x8 a = ld_frag(&h2frag[((mt*2 + kt)*64 + lane)*8]);
          acc3[mt] = mfma16(a, b0, acc3[mt]);
        }
      }
      {
        int col = wid*16 + l15;
        float bias = eb3[ei*64 + col];
        #pragma unroll
        for (int mt = 0; mt < 4; ++mt)
          #pragma unroll
          for (int rr = 0; rr < 4; ++rr) {
            int m = mt*16 + rl + rr;
            fbuf[((m >> 5)*32 + (m & 31))*68 + col] = acc3[mt][rr] + bias;
          }
      }
      __syncthreads();  // E3

      // LayerNorm + self-gate diag + weighted aggregate (thread: row mL, 16 cols qc*16..)
      {
        float v[16];
        #pragma unroll
        for (int cc = 0; cc < 4; ++cc) {
          float4 f = *(const float4*)&fbuf[(tkL*32 + mrL)*68 + qc*16 + cc*4];
          v[cc*4+0] = f.x; v[cc*4+1] = f.y; v[cc*4+2] = f.z; v[cc*4+3] = f.w;
        }
        float s1 = 0.f;
        #pragma unroll
        for (int c = 0; c < 16; ++c) s1 += v[c];
        s1 += __shfl_xor(s1, 1); s1 += __shfl_xor(s1, 2);
        float mu = s1 * (1.f/64.f);
        float s2 = 0.f;
        #pragma unroll
        for (int c = 0; c < 16; ++c) { float d = v[c] - mu; s2 += d*d; }
        s2 += __shfl_xor(s2, 1); s2 += __shfl_xor(s2, 2);
        float rs = rsqrtf(s2 * (1.f/64.f) + 1e-5f);
        const int tgL = g*2 + tkL;
        const float* lsp = lns + ei*64 + qc*16;
        const float* lbp = lnb + ei*64 + qc*16;
        const float* sgp = sgW + (tgL*64 + qc*16)*4 + el;
        float swp = 0.f;
        #pragma unroll
        for (int c = 0; c < 16; ++c) {
          float eh = (v[c] - mu) * rs * lsp[c] + lbp[c];
          v[c] = eh;
          swp += eh * sgp[c*4];
        }
        swp += __shfl_xor(swp, 1); swp += __shfl_xor(swp, 2);
        swp += sgb[tgL*4 + el];
        float fac = swp * gwbuf[tkL*128 + mrL*4 + el];
        #pragma unroll
        for (int c = 0; c < 16; ++c) agg[c] += v[c] * fac;
      }
      // no trailing barrier: next GEMM1 writes h1frag (disjoint from fbuf/gwbuf); E1 orders.
    }  // expert loop

    // ---------- tower: agg(64x64) -> T1 (per task 32x64) -> T2 (32x32) -> out ----------
    {
      // write agg as A-frags: thread row mL, feats qc*16+0..15 (2 b128)
      #pragma unroll
      for (int jh = 0; jh < 2; ++jh) {
        uint4 wv;
        wv.x = f2bf2(agg[jh*8+0], agg[jh*8+1]);
        wv.y = f2bf2(agg[jh*8+2], agg[jh*8+3]);
        wv.z = f2bf2(agg[jh*8+4], agg[jh*8+5]);
        wv.w = f2bf2(agg[jh*8+6], agg[jh*8+7]);
        int tile = (mL >> 4)*2 + (qc >> 1);
        int slot = (mL & 15) + 16*((qc & 1)*2 + jh);
        *(uint4*)&aggfrag[(tile*64 + slot)*8] = wv;
      }
    }
    // prefetch tw_W1 kt0 for both of this wave's n-tiles
    const u16* tw1b = pk + OFF_TW1 + ((tg0*4 + chw*2)*2)*512 + lane*8;
    U4 t1f0, t1f1;
    t1f0.u = *(const uint4*)tw1b;
    t1f1.u = *(const uint4*)(tw1b + 1024);
    __syncthreads();  // F

    // T1: wave (task tkw) computes n-tiles chw*2, chw*2+1 of its task's 64 cols
    {
      f32x4 at1[2][2] = { { fz, fz }, { fz, fz } };   // [mtl][nt2]
      #pragma unroll
      for (int kt = 0; kt < 2; ++kt) {
        bf16x8 b0 = (kt == 0) ? t1f0.v : ld_frag(tw1b + kt*512);
        bf16x8 b1 = (kt == 0) ? t1f1.v : ld_frag(tw1b + 1024 + kt*512);
        #pragma unroll
        for (int mtl = 0; mtl < 2; ++mtl) {
          bf16x8 a = ld_frag(&aggfrag[(((2*tkw + mtl)*2 + kt)*64 + lane)*8]);
          at1[mtl][0] = mfma16(a, b0, at1[mtl][0]);
          at1[mtl][1] = mfma16(a, b1, at1[mtl][1]);
        }
      }
      #pragma unroll
      for (int nt2 = 0; nt2 < 2; ++nt2) {
        int colT = (chw*2 + nt2)*16 + l15;
        float bias = twb1[tg0*64 + colT];
        int ktT = colT >> 5, hT = (colT >> 3) & 3, iT = colT & 7;
        #pragma unroll
        for (int mtl = 0; mtl < 2; ++mtl)
          #pragma unroll
          for (int rr = 0; rr < 4; ++rr)
            th1frag[tkw*2048 + ((mtl*2 + ktT)*64 + rl + rr + 16*hT)*8 + iT] =
                f2bf(swishf(at1[mtl][nt2][rr] + bias));
      }
    }
    __syncthreads();  // G

    // T2 + output: wave w<2 handles task w entirely (both 16-col tiles), writes out.
    if (wid < 2) {
      const int tg = g*2 + wid;
      f32x4 at2[2][2] = { { fz, fz }, { fz, fz } };   // [nt][mtl]
      const u16* tw2p = pk + OFF_TW2 + (tg*2*2)*512 + lane*8;
      #pragma unroll
      for (int kt = 0; kt < 2; ++kt) {
        bf16x8 b0 = ld_frag(tw2p + kt*512);
        bf16x8 b1 = ld_frag(tw2p + 1024 + kt*512);
        #pragma unroll
        for (int mtl = 0; mtl < 2; ++mtl) {
          bf16x8 a = ld_frag(&th1frag[wid*2048 + ((mtl*2 + kt)*64 + lane)*8]);
          at2[0][mtl] = mfma16(a, b0, at2[0][mtl]);
          at2[1][mtl] = mfma16(a, b1, at2[1][mtl]);
        }
      }
      float pxs[8];
      #pragma unroll
      for (int nt = 0; nt < 2; ++nt) {
        int colU = nt*16 + l15;
        float b2  = twb2[tg*32 + colU];
        float w3v = twW3[tg*32 + colU];
        #pragma unroll
        for (int mtl = 0; mtl < 2; ++mtl)
          #pragma unroll
          for (int rr = 0; rr < 4; ++rr) {
            float val = swishf(at2[nt][mtl][rr] + b2) * w3v;
            if (nt == 0) pxs[mtl*4 + rr] = val;
            else         pxs[mtl*4 + rr] += val;
          }
      }
      #pragma unroll
      for (int k = 0; k < 8; ++k) {
        pxs[k] += __shfl_xor(pxs[k], 1);
        pxs[k] += __shfl_xor(pxs[k], 2);
        pxs[k] += __shfl_xor(pxs[k], 4);
        pxs[k] += __shfl_xor(pxs[k], 8);
      }
      if (l15 == 0) {
        float b3 = twb3[tg];
        #pragma unroll
        for (int mtl = 0; mtl < 2; ++mtl)
          #pragma unroll
          for (int rr = 0; rr < 4; ++rr) {
            int row = mtl*16 + rl + rr;
            float x = pxs[mtl*4 + rr] + b3;
            out[(size_t)(rowBase + row)*4 + tg] = sig1(x);
          }
      }
    }
    // no trailing barrier: next pair's staging writes cmfrag/smallw whose last readers
    // (GEMM1 el3 / softmax) are many barriers back; th1frag (fbuf) readers here are
    // waves 0,1 only, and next writes to that region (tg1 epilogue) are behind A/A2/A3.
  }
}

extern "C" void kernel_launch(void* const* d_in, const int* in_sizes, int n_in,
                              void* d_out, int out_size, void* d_ws, size_t ws_size,
                              hipStream_t stream)
{
  (void)in_sizes; (void)n_in; (void)out_size; (void)ws_size;
  const float* zs   = (const float*)d_in[0];
  const float* zg0  = (const float*)d_in[1];
  const float* zg1  = (const float*)d_in[2];
  // d_in[3] = v : unused by the reference
  const float* eW1  = (const float*)d_in[4];
  const float* eb1  = (const float*)d_in[5];
  const float* eW2  = (const float*)d_in[6];
  const float* eb2  = (const float*)d_in[7];
  const float* eW3  = (const float*)d_in[8];
  const float* eb3  = (const float*)d_in[9];
  const float* lns  = (const float*)d_in[10];
  const float* lnb  = (const float*)d_in[11];
  const float* fgA  = (const float*)d_in[12];
  const float* fgB  = (const float*)d_in[13];
  const float* tgW1 = (const float*)d_in[14];
  const float* tgb1 = (const float*)d_in[15];
  const float* tgW2 = (const float*)d_in[16];
  const float* tgb2 = (const float*)d_in[17];
  const float* sgW  = (const float*)d_in[18];
  const float* sgb  = (const float*)d_in[19];
  const float* twW1 = (const float*)d_in[20];
  const float* twb1 = (const float*)d_in[21];
  const float* twW2 = (const float*)d_in[22];
  const float* twb2 = (const float*)d_in[23];
  const float* twW3 = (const float*)d_in[24];
  const float* twb3 = (const float*)d_in[25];

  u16* pkw = (u16*)d_ws;          // needs 819200 B
  float* outp = (float*)d_out;

  prep_pack<<<(NPACK + 255)/256, 256, 0, stream>>>(eW1, eW2, eW3, tgW1, twW1, twW2, fgA, fgB, pkw);
  home_main<<<65536/32, 256, 0, stream>>>(zs, zg0, zg1, tgW2, tgb1, tgb2,
      eb1, eb2, eb3, lns, lnb, sgW, sgb, twb1, twb2, twW3, twb3,
      pkw, outp);
}